// Round 12
// baseline (330.014 us; speedup 1.0000x reference)
//
#include <hip/hip_runtime.h>
#include <hip/hip_bf16.h>

// Problem constants
#define BB   2
#define LI   1024
#define LC   256
#define SEQ  1280      // LC + LI
#define HDIM 1024
#define NH   16
#define HD   64
#define MLPD 4096
#define EPS  1e-6f
#define MROWS 2560     // 2048 img rows then 512 cond rows
#define MTI  16        // img M-tiles (BM=128)
#define MTT  20        // total M-tiles (16 img + 4 cond)

typedef __bf16 bf16x8 __attribute__((ext_vector_type(8)));
typedef float f32x4 __attribute__((ext_vector_type(4)));
typedef unsigned short us4 __attribute__((ext_vector_type(4)));

static __device__ __forceinline__ unsigned short f2bf(float f) {
    unsigned int u = __builtin_bit_cast(unsigned int, f);
    u += 0x7fffu + ((u >> 16) & 1u);
    return (unsigned short)(u >> 16);
}

// async global->LDS, 16B per lane. LDS dst = wave-uniform base + lane*16.
static __device__ __forceinline__ void gload_lds16(const void* g, void* l) {
    __builtin_amdgcn_global_load_lds((__attribute__((address_space(1))) void*)(g),
                                     (__attribute__((address_space(3))) void*)(l),
                                     16, 0, 0);
}

// ---------------------------------------------------------------------------
// One-shot weight pack + norm1. Segs 0/1: interleave w1/w2 (16-col groups) into
// pair layout [8192][1024]; segs 2-7: plain f32->bf16 cvt; seg 8: rmsnorm1
// (4 rows per block) -> xn bf16 [2560][1024].
__global__ __launch_bounds__(256)
void pack_weights(const float* __restrict__ w1i, const float* __restrict__ w2i,
                  const float* __restrict__ w1c, const float* __restrict__ w2c,
                  const float* __restrict__ w3i, const float* __restrict__ w3c,
                  const float* __restrict__ wqi, const float* __restrict__ wqc,
                  const float* __restrict__ woi, const float* __restrict__ woc,
                  unsigned short* __restrict__ wpi, unsigned short* __restrict__ wpc,
                  unsigned short* __restrict__ w3bi, unsigned short* __restrict__ w3bc,
                  unsigned short* __restrict__ wqbi, unsigned short* __restrict__ wqbc,
                  unsigned short* __restrict__ wobi, unsigned short* __restrict__ wobc,
                  const float* __restrict__ img_tok, const float* __restrict__ cond_tok,
                  const float* __restrict__ n1wi, const float* __restrict__ n1wc,
                  unsigned short* __restrict__ xn)
{
    const int seg = blockIdx.y;
    const int t = threadIdx.x;

    if (seg == 8) {   // rmsnorm1: rows blockIdx.x*4 .. +3
        __shared__ float red[4];
#pragma unroll
        for (int rr = 0; rr < 4; ++rr) {
            const int row = blockIdx.x * 4 + rr;
            const float* x = (row < 2048) ? img_tok + (size_t)row * HDIM
                                          : cond_tok + (size_t)(row - 2048) * HDIM;
            const float* w = (row < 2048) ? n1wi : n1wc;
            float4 v = ((const float4*)x)[t];
            float ss = v.x*v.x + v.y*v.y + v.z*v.z + v.w*v.w;
            for (int o = 32; o > 0; o >>= 1) ss += __shfl_xor(ss, o);
            if ((t & 63) == 0) red[t >> 6] = ss;
            __syncthreads();
            float inv = rsqrtf((red[0]+red[1]+red[2]+red[3]) * (1.0f / HDIM) + EPS);
            float4 wv = ((const float4*)w)[t];
            us4 pk = { f2bf(v.x*inv*wv.x), f2bf(v.y*inv*wv.y),
                       f2bf(v.z*inv*wv.z), f2bf(v.w*inv*wv.w) };
            *(us4*)&xn[(size_t)row * HDIM + t * 4] = pk;
            __syncthreads();   // red reused next iteration
        }
        return;
    }

    const float* s0 = nullptr; const float* s1 = nullptr;
    unsigned short* dst = nullptr; int n4 = 0; bool pair = false;
    switch (seg) {
        case 0: pair = true; s0 = w1i; s1 = w2i; dst = wpi;  n4 = 8388608 / 4; break;
        case 1: pair = true; s0 = w1c; s1 = w2c; dst = wpc;  n4 = 8388608 / 4; break;
        case 2: s0 = w3i; dst = w3bi; n4 = 4194304 / 4; break;
        case 3: s0 = w3c; dst = w3bc; n4 = 4194304 / 4; break;
        case 4: s0 = wqi; dst = wqbi; n4 = 3145728 / 4; break;
        case 5: s0 = wqc; dst = wqbc; n4 = 3145728 / 4; break;
        case 6: s0 = woi; dst = wobi; n4 = 1048576 / 4; break;
        case 7: s0 = woc; dst = wobc; n4 = 1048576 / 4; break;
    }
    for (int i = blockIdx.x * 256 + t; i < n4; i += gridDim.x * 256) {
        float4 v;
        if (pair) {
            int p  = i >> 8;          // phys row (256 float4 per 1024-row)
            int k4 = i & 255;
            int g = p >> 4, r = p & 15;
            const float* s = (g & 1) ? s1 : s0;
            v = *(const float4*)&s[((size_t)((g >> 1) * 16 + r)) * 1024 + k4 * 4];
        } else {
            v = ((const float4*)s0)[i];
        }
        us4 o = { f2bf(v.x), f2bf(v.y), f2bf(v.z), f2bf(v.w) };
        ((us4*)dst)[i] = o;
    }
}

// ---------------------------------------------------------------------------
// Fused norm2 + down-proj init. val = tok + sa*op;
// n2 = rmsnorm(val)*w (bf16);  out = val + sm*b3 (f32, split-K target).
__global__ __launch_bounds__(256)
void norm2_down(const float* __restrict__ img_tok, const float* __restrict__ cond_tok,
                const float* __restrict__ op, const float* __restrict__ wi,
                const float* __restrict__ wc, const float* __restrict__ b3i,
                const float* __restrict__ b3c, const float* __restrict__ alpha,
                const float* __restrict__ beta,
                unsigned short* __restrict__ n2, float* __restrict__ out)
{
    const int row = blockIdx.x;
    const int t   = threadIdx.x;
    const bool img = row < 2048;
    const float sa = img ? alpha[0] : 1.0f;
    const float sm = img ? beta[0]  : 1.0f;
    const float* tok = img ? img_tok + (size_t)row * HDIM
                           : cond_tok + (size_t)(row - 2048) * HDIM;
    const float* w  = img ? wi  : wc;
    const float* b3 = img ? b3i : b3c;
    float4 tv = ((const float4*)tok)[t];
    float4 ov = ((const float4*)(op + (size_t)row * HDIM))[t];
    float4 v = { tv.x + sa*ov.x, tv.y + sa*ov.y, tv.z + sa*ov.z, tv.w + sa*ov.w };
    float ss = v.x*v.x + v.y*v.y + v.z*v.z + v.w*v.w;
    for (int o = 32; o > 0; o >>= 1) ss += __shfl_xor(ss, o);
    __shared__ float red[4];
    if ((t & 63) == 0) red[t >> 6] = ss;
    __syncthreads();
    float inv = rsqrtf((red[0]+red[1]+red[2]+red[3]) * (1.0f / HDIM) + EPS);
    float4 wv = ((const float4*)w)[t];
    us4 pk = { f2bf(v.x*inv*wv.x), f2bf(v.y*inv*wv.y),
               f2bf(v.z*inv*wv.z), f2bf(v.w*inv*wv.w) };
    *(us4*)&n2[(size_t)row * HDIM + t * 4] = pk;
    float4 bv = ((const float4*)b3)[t];
    float4 o4 = { v.x + sm*bv.x, v.y + sm*bv.y, v.z + sm*bv.z, v.w + sm*bv.w };
    ((float4*)(out + (size_t)row * HDIM))[t] = o4;
}

// op = bias (broadcast), per-stream bias
__global__ __launch_bounds__(256)
void op_init(const float* __restrict__ bi, const float* __restrict__ bc,
             float* __restrict__ op)
{
    const int row = blockIdx.x, t = threadIdx.x;
    const float* b = (row < 2048) ? bi : bc;
    ((float4*)(op + (size_t)row * HDIM))[t] = ((const float4*)b)[t];
}

// ---------------------------------------------------------------------------
// Grouped QKV GEMM with FUSED per-head RMSNorm+RoPE epilogue (R9-proven).
// 1-D grid 480, XCD remap. 2-barrier BK=32 K-loop.
__global__ __launch_bounds__(256)
void qkv_gemm(const unsigned short* __restrict__ xn,
              const unsigned short* __restrict__ wqi, const unsigned short* __restrict__ wqc,
              const float* __restrict__ bi, const float* __restrict__ bc,
              const float* __restrict__ img_qn, const float* __restrict__ img_kn,
              const float* __restrict__ cond_qn, const float* __restrict__ cond_kn,
              const float* __restrict__ icos, const float* __restrict__ isin,
              const float* __restrict__ ccos, const float* __restrict__ csin,
              unsigned short* __restrict__ qh, unsigned short* __restrict__ kh,
              unsigned short* __restrict__ vt)
{
    __shared__ __align__(16) unsigned short As[128][32];
    __shared__ __align__(16) unsigned short Ws[128][32];

    const int id  = blockIdx.x;
    const int xcd = id & 7, idx = id >> 3;           // 8 x 60
    const int xcol = xcd * 3 + idx / 20;             // 0..23
    const int mt   = idx % 20;
    const bool img = mt < MTI;
    const int row0 = img ? mt * 128 : 2048 + (mt - MTI) * 128;
    const int grow0 = img ? mt * 128 : (mt - MTI) * 128;
    const unsigned short* W = img ? wqi : wqc;
    const float* bias = img ? bi : bc;
    const int bn = xcol * 128;

    const int t = threadIdx.x, lane = t & 63, wid = t >> 6;
    const int wm = wid >> 1, wn = wid & 1;
    const int srow = (wid << 5) + (lane >> 2);
    const int scol = (lane & 3) << 3;
    const unsigned short* Ag0 = xn + (size_t)(row0 + srow)      * HDIM + scol;
    const unsigned short* Ag1 = xn + (size_t)(row0 + srow + 16) * HDIM + scol;
    const unsigned short* Wg0 = W  + (size_t)(bn + srow)        * HDIM + scol;
    const unsigned short* Wg1 = W  + (size_t)(bn + srow + 16)   * HDIM + scol;
    unsigned short* lA0 = &As[(wid << 5)     ][0];
    unsigned short* lA1 = &As[(wid << 5) + 16][0];
    unsigned short* lW0 = &Ws[(wid << 5)     ][0];
    unsigned short* lW1 = &Ws[(wid << 5) + 16][0];

    const int fr = lane & 15, kg = lane >> 4, ko = kg << 3;
    f32x4 acc[4][4] = {};

    for (int k0 = 0; k0 < HDIM; k0 += 32) {
        __syncthreads();
        gload_lds16(Ag0 + k0, lA0);
        gload_lds16(Ag1 + k0, lA1);
        gload_lds16(Wg0 + k0, lW0);
        gload_lds16(Wg1 + k0, lW1);
        __syncthreads();
        bf16x8 aF[4], bF[4];
#pragma unroll
        for (int m = 0; m < 4; ++m) aF[m] = *(const bf16x8*)&As[wm*64 + m*16 + fr][ko];
#pragma unroll
        for (int n = 0; n < 4; ++n) bF[n] = *(const bf16x8*)&Ws[wn*64 + n*16 + fr][ko];
#pragma unroll
        for (int m = 0; m < 4; ++m)
#pragma unroll
            for (int n = 0; n < 4; ++n)
                acc[m][n] = __builtin_amdgcn_mfma_f32_16x16x32_bf16(aF[m], bF[n], acc[m][n], 0,0,0);
    }

    // ---- epilogue: wave-uniform head / q-k-v selector ----
    const int gcbase = bn + wn * 64;     // 64-aligned, uniform per wave
    const int which  = gcbase >> 10;     // 0 q / 1 k / 2 v
    const int h      = (gcbase >> 6) & 15;

    if (which == 2) {
#pragma unroll
        for (int n = 0; n < 4; ++n) {
            const int d = n*16 + fr;
            const float bv = bias[gcbase + d];
#pragma unroll
            for (int m = 0; m < 4; ++m) {
                const int gl0 = grow0 + wm*64 + m*16 + (kg << 2);
                int b, s0;
                if (img) { b = gl0 >> 10; s0 = LC + (gl0 & 1023); }
                else     { b = gl0 >> 8;  s0 = gl0 & 255; }
                us4 pk = { f2bf(acc[m][n][0] + bv), f2bf(acc[m][n][1] + bv),
                           f2bf(acc[m][n][2] + bv), f2bf(acc[m][n][3] + bv) };
                *(us4*)&vt[(((size_t)(b*NH + h)) * HD + d) * SEQ + s0] = pk;
            }
        }
    } else {
        unsigned short* dst = (which == 0) ? qh : kh;
        const float qscale = (which == 0) ? 0.125f : 1.0f;
        const float* nw = img ? (which == 0 ? img_qn : img_kn)
                              : (which == 0 ? cond_qn : cond_kn);
        const float* cs_tab = img ? icos : ccos;
        const float* sn_tab = img ? isin : csin;
        float wv[4], bv[4];
#pragma unroll
        for (int nt = 0; nt < 4; ++nt) {
            wv[nt] = nw[nt*16 + fr];
            bv[nt] = bias[gcbase + nt*16 + fr];
        }
#pragma unroll
        for (int m = 0; m < 4; ++m) {
#pragma unroll
            for (int j = 0; j < 4; ++j) {
                const int gl = grow0 + wm*64 + m*16 + (kg << 2) + j;
                int b, srel, s;
                if (img) { b = gl >> 10; srel = gl & 1023; s = LC + srel; }
                else     { b = gl >> 8;  srel = gl & 255;  s = srel; }
                float v[4];
                float ss = 0.f;
#pragma unroll
                for (int nt = 0; nt < 4; ++nt) {
                    v[nt] = acc[m][nt][j] + bv[nt];
                    ss += v[nt] * v[nt];
                }
                ss += __shfl_xor(ss, 1);
                ss += __shfl_xor(ss, 2);
                ss += __shfl_xor(ss, 4);
                ss += __shfl_xor(ss, 8);
                const float inv = rsqrtf(ss * (1.0f / HD) + EPS);
                float xv[4];
#pragma unroll
                for (int nt = 0; nt < 4; ++nt) xv[nt] = v[nt] * inv * wv[nt];
                const size_t obase = (((size_t)(b*NH + h)) * SEQ + s) * HD;
#pragma unroll
                for (int nt = 0; nt < 4; ++nt) {
                    const int d = nt*16 + fr;
                    const float rot = (nt < 2) ? -xv[nt + 2] : xv[nt - 2];
                    const float c  = cs_tab[(size_t)srel * HD + d];
                    const float sn = sn_tab[(size_t)srel * HD + d];
                    dst[obase + d] = f2bf((xv[nt] * c + rot * sn) * qscale);
                }
            }
        }
    }
}

// ---------------------------------------------------------------------------
// Grouped pair GEMM (R6-proven form). 1-D grid 1280, XCD remap: xcd owns 8
// col-tiles. 2-barrier BK=32 K-loop. swiglu epilogue -> hbf.
__global__ __launch_bounds__(256)
void pair_gemm(const unsigned short* __restrict__ n2,
               const unsigned short* __restrict__ wpi, const unsigned short* __restrict__ wpc,
               const float* __restrict__ b1i, const float* __restrict__ b2i,
               const float* __restrict__ b1c, const float* __restrict__ b2c,
               unsigned short* __restrict__ hbf)
{
    __shared__ __align__(16) unsigned short As[128][32];
    __shared__ __align__(16) unsigned short Ws[128][32];

    const int id  = blockIdx.x;
    const int xcd = id & 7, idx = id >> 3;           // 8 x 160
    const int x   = xcd * 8 + idx / 20;              // phys col tile 0..63
    const int mt  = idx % 20;
    const bool img = mt < MTI;
    const int row0 = img ? mt * 128 : 2048 + (mt - MTI) * 128;
    const unsigned short* W = img ? wpi : wpc;
    const float* b1 = img ? b1i : b1c;
    const float* b2 = img ? b2i : b2c;
    const int bn = x * 128;

    const int t = threadIdx.x, lane = t & 63, wid = t >> 6;
    const int wm = wid >> 1, wn = wid & 1;
    const int srow = (wid << 5) + (lane >> 2);
    const int scol = (lane & 3) << 3;
    const unsigned short* Ag0 = n2 + (size_t)(row0 + srow)      * HDIM + scol;
    const unsigned short* Ag1 = n2 + (size_t)(row0 + srow + 16) * HDIM + scol;
    const unsigned short* Wg0 = W  + (size_t)(bn + srow)        * HDIM + scol;
    const unsigned short* Wg1 = W  + (size_t)(bn + srow + 16)   * HDIM + scol;
    unsigned short* lA0 = &As[(wid << 5)     ][0];
    unsigned short* lA1 = &As[(wid << 5) + 16][0];
    unsigned short* lW0 = &Ws[(wid << 5)     ][0];
    unsigned short* lW1 = &Ws[(wid << 5) + 16][0];

    const int fr = lane & 15, kg = lane >> 4, ko = kg << 3;
    f32x4 acc[4][4] = {};

    for (int k0 = 0; k0 < HDIM; k0 += 32) {
        __syncthreads();
        gload_lds16(Ag0 + k0, lA0);
        gload_lds16(Ag1 + k0, lA1);
        gload_lds16(Wg0 + k0, lW0);
        gload_lds16(Wg1 + k0, lW1);
        __syncthreads();
        bf16x8 aF[4], bF[4];
#pragma unroll
        for (int m = 0; m < 4; ++m) aF[m] = *(const bf16x8*)&As[wm*64 + m*16 + fr][ko];
#pragma unroll
        for (int n = 0; n < 4; ++n) bF[n] = *(const bf16x8*)&Ws[wn*64 + n*16 + fr][ko];
#pragma unroll
        for (int m = 0; m < 4; ++m)
#pragma unroll
            for (int n = 0; n < 4; ++n)
                acc[m][n] = __builtin_amdgcn_mfma_f32_16x16x32_bf16(aF[m], bF[n], acc[m][n], 0,0,0);
    }

    // epilogue: pairs (nt=0,1) and (nt=2,3): logical col lc = (4x+2wn+p)*16+fr
#pragma unroll
    for (int p = 0; p < 2; ++p) {
        const int lc = (4*x + 2*wn + p) * 16 + fr;        // 0..4095
        const float b1v = b1[lc], b2v = b2[lc];
#pragma unroll
        for (int m = 0; m < 4; ++m) {
#pragma unroll
            for (int j = 0; j < 4; ++j) {
                const int row = row0 + wm*64 + m*16 + (kg << 2) + j;
                float g1 = acc[m][2*p    ][j] + b1v;
                float g2 = acc[m][2*p + 1][j] + b2v;
                float hv = (g1 / (1.0f + __expf(-g1))) * g2;
                hbf[(size_t)row * MLPD + lc] = f2bf(hv);
            }
        }
    }
}

// ---------------------------------------------------------------------------
// Grouped split-K GEMM, 128x128, N=1024, BK=32 (R9-proven). 1-D grid 8*20*Z,
// XCD remap: xcd owns one bn-panel. Epilogue: out += sc*acc via f32 atomics.
__global__ __launch_bounds__(256)
void skg_gemm(const unsigned short* __restrict__ A, int K,
              const unsigned short* __restrict__ Wimg, const unsigned short* __restrict__ Wcond,
              float* __restrict__ out, int kchunk,
              const float* __restrict__ sci, const float* __restrict__ scc)
{
    __shared__ __align__(16) unsigned short As[128][32];
    __shared__ __align__(16) unsigned short Ws[128][32];

    const int id  = blockIdx.x;
    const int xcd = id & 7, idx = id >> 3;
    const int bn  = xcd * 128;
    const int mt  = idx % 20;
    const int kz  = idx / 20;
    const bool img = mt < MTI;
    const int row0 = img ? mt * 128 : 2048 + (mt - MTI) * 128;
    const unsigned short* W = img ? Wimg : Wcond;
    const float sc = img ? (sci ? sci[0] : 1.0f) : (scc ? scc[0] : 1.0f);
    const int kbase = kz * kchunk;

    const int t = threadIdx.x, lane = t & 63, wid = t >> 6;
    const int wm = wid >> 1, wn = wid & 1;
    const int srow = (wid << 5) + (lane >> 2);
    const int scol = (lane & 3) << 3;
    const unsigned short* Ag0 = A + (size_t)(row0 + srow)      * K + kbase + scol;
    const unsigned short* Ag1 = A + (size_t)(row0 + srow + 16) * K + kbase + scol;
    const unsigned short* Wg0 = W + (size_t)(bn + srow)        * K + kbase + scol;
    const unsigned short* Wg1 = W + (size_t)(bn + srow + 16)   * K + kbase + scol;
    unsigned short* lA0 = &As[(wid << 5)     ][0];
    unsigned short* lA1 = &As[(wid << 5) + 16][0];
    unsigned short* lW0 = &Ws[(wid << 5)     ][0];
    unsigned short* lW1 = &Ws[(wid << 5) + 16][0];

    const int fr = lane & 15, kg = lane >> 4, ko = kg << 3;
    f32x4 acc[4][4] = {};

    for (int k0 = 0; k0 < kchunk; k0 += 32) {
        __syncthreads();
        gload_lds16(Ag0 + k0, lA0);
        gload_lds16(Ag1 + k0, lA1);
        gload_lds16(Wg0 + k0, lW0);
        gload_lds16(Wg1 + k0, lW1);
        __syncthreads();
        bf16x8 aF[4], bF[4];
#pragma unroll
        for (int m = 0; m < 4; ++m) aF[m] = *(const bf16x8*)&As[wm*64 + m*16 + fr][ko];
#pragma unroll
        for (int n = 0; n < 4; ++n) bF[n] = *(const bf16x8*)&Ws[wn*64 + n*16 + fr][ko];
#pragma unroll
        for (int m = 0; m < 4; ++m)
#pragma unroll
            for (int n = 0; n < 4; ++n)
                acc[m][n] = __builtin_amdgcn_mfma_f32_16x16x32_bf16(aF[m], bF[n], acc[m][n], 0,0,0);
    }

#pragma unroll
    for (int n = 0; n < 4; ++n) {
        const int col = bn + wn*64 + n*16 + fr;
#pragma unroll
        for (int m = 0; m < 4; ++m) {
            const int r0 = row0 + wm*64 + m*16 + (kg << 2);
#pragma unroll
            for (int j = 0; j < 4; ++j)
                unsafeAtomicAdd(&out[(size_t)(r0 + j) * HDIM + col], sc * acc[m][n][j]);
        }
    }
}

// ---------------------------------------------------------------------------
// MFMA flash attention: 256 thr (4 waves), q-tile 128. 1-D grid 320 with
// XCD remap (4 bh per XCD -> K/V L2-resident). Double-buffered staging;
// S^T = mfma(K,Q); packed us4 P writes.
__global__ __launch_bounds__(256)
void attn_mfma(const unsigned short* __restrict__ qg,
               const unsigned short* __restrict__ kg,
               const unsigned short* __restrict__ vtg,
               unsigned short* __restrict__ o)
{
    const int id  = blockIdx.x;
    const int xcd = id & 7, idx = id >> 3;     // 8 x 40
    const int bh  = xcd * 4 + idx / 10;        // 0..31
    const int q0  = (idx % 10) * 128;
    const int h   = bh & 15;
    const int b   = bh >> 4;
    const int t   = threadIdx.x;
    const int wid = t >> 6;
    const int lane = t & 63;
    const int g  = lane >> 4;
    const int fr = lane & 15;

    __shared__ __align__(16) unsigned short Ks [2][64 * 64];
    __shared__ __align__(16) unsigned short VTs[2][64 * 64];
    __shared__ __align__(16) unsigned short Ps [4][32][72];

    const unsigned short* qb  = qg  + (size_t)bh * SEQ * HD;
    const unsigned short* kb  = kg  + (size_t)bh * SEQ * HD;
    const unsigned short* vtb = vtg + (size_t)bh * HD * SEQ;

    bf16x8 Qf[2][2];
#pragma unroll
    for (int mt = 0; mt < 2; ++mt)
#pragma unroll
        for (int kc = 0; kc < 2; ++kc)
            Qf[mt][kc] = *(const bf16x8*)&qb[(size_t)(q0 + wid*32 + mt*16 + fr) * HD
                                             + kc*32 + g*8];

    f32x4 O[2][4] = {};
    float mreg[2] = { -3e38f, -3e38f };
    float lreg[2] = { 0.f, 0.f };

#define STAGE(tile_, bufi_)                                                     \
    {                                                                           \
        _Pragma("unroll")                                                       \
        for (int i = 0; i < 2; ++i) {                                           \
            int chbase = i * 256 + wid * 64;                                    \
            int ch = chbase + lane;                                             \
            int r = ch >> 3, c = ch & 7;                                        \
            int cs_ = c ^ (r & 7);                                              \
            gload_lds16(kb  + (size_t)((tile_)*64 + r) * HD + cs_*8,            \
                        &Ks[bufi_][chbase * 8]);                                \
            gload_lds16(vtb + (size_t)r * SEQ + (tile_)*64 + cs_*8,             \
                        &VTs[bufi_][chbase * 8]);                               \
        }                                                                       \
    }

    STAGE(0, 0);
    __syncthreads();
    int buf = 0;

    for (int tile = 0; tile < SEQ / 64; ++tile) {
        if (tile + 1 < SEQ / 64) STAGE(tile + 1, buf ^ 1);

        f32x4 ST[2][4] = {};
#pragma unroll
        for (int kc = 0; kc < 2; ++kc)
#pragma unroll
            for (int nt = 0; nt < 4; ++nt) {
                int r = fr + 16*nt;
                bf16x8 kf = *(const bf16x8*)&Ks[buf][r*64 + (((g + 4*kc) ^ (r & 7)) * 8)];
#pragma unroll
                for (int mt = 0; mt < 2; ++mt)
                    ST[mt][nt] = __builtin_amdgcn_mfma_f32_16x16x32_bf16(
                        kf, Qf[mt][kc], ST[mt][nt], 0, 0, 0);
            }

#pragma unroll
        for (int mt = 0; mt < 2; ++mt) {
            float tm = -3e38f;
#pragma unroll
            for (int nt = 0; nt < 4; ++nt)
#pragma unroll
                for (int j = 0; j < 4; ++j) tm = fmaxf(tm, ST[mt][nt][j]);
            tm = fmaxf(tm, __shfl_xor(tm, 16));
            tm = fmaxf(tm, __shfl_xor(tm, 32));
            float mn = fmaxf(mreg[mt], tm);
            float al = __expf(mreg[mt] - mn);
            mreg[mt] = mn;
            float ls = 0.f;
#pragma unroll
            for (int nt = 0; nt < 4; ++nt) {
#pragma unroll
                for (int j = 0; j < 4; ++j) {
                    float p = __expf(ST[mt][nt][j] - mn);
                    ST[mt][nt][j] = p;
                    ls += p;
                }
            }
            ls += __shfl_xor(ls, 16);
            ls += __shfl_xor(ls, 32);
            lreg[mt] = al * lreg[mt] + ls;
            f32x4 alr;
#pragma unroll
            for (int rg = 0; rg < 4; ++rg) alr[rg] = __shfl(al, 4*g + rg);
#pragma unroll
            for (int dt = 0; dt < 4; ++dt) O[mt][dt] *= alr;
#pragma unroll
            for (int nt = 0; nt < 4; ++nt) {
                us4 pk = { f2bf(ST[mt][nt][0]), f2bf(ST[mt][nt][1]),
                           f2bf(ST[mt][nt][2]), f2bf(ST[mt][nt][3]) };
                *(us4*)&Ps[wid][mt*16 + fr][16*nt + 4*g] = pk;
            }
        }

#pragma unroll
        for (int kc = 0; kc < 2; ++kc) {
            bf16x8 Pf[2];
#pragma unroll
            for (int mt = 0; mt < 2; ++mt)
                Pf[mt] = *(const bf16x8*)&Ps[wid][mt*16 + fr][kc*32 + g*8];
#pragma unroll
            for (int dt = 0; dt < 4; ++dt) {
                int r = fr + 16*dt;
                bf16x8 vf = *(const bf16x8*)&VTs[buf][r*64 + (((g + 4*kc) ^ (r & 7)) * 8)];
#pragma unroll
                for (int mt = 0; mt < 2; ++mt)
                    O[mt][dt] = __builtin_amdgcn_mfma_f32_16x16x32_bf16(
                        Pf[mt], vf, O[mt][dt], 0, 0, 0);
            }
        }

        __syncthreads();
        buf ^= 1;
    }

#pragma unroll
    for (int mt = 0; mt < 2; ++mt) {
        const float linv = 1.0f / lreg[mt];
        f32x4 lv;
#pragma unroll
        for (int rg = 0; rg < 4; ++rg) lv[rg] = __shfl(linv, 4*g + rg);
#pragma unroll
        for (int rg = 0; rg < 4; ++rg) {
            const int s_tok = q0 + wid*32 + mt*16 + 4*g + rg;
            const size_t row = (s_tok < LC) ? (size_t)(2048 + b*LC + s_tok)
                                            : (size_t)(b*LI + (s_tok - LC));
#pragma unroll
            for (int dt = 0; dt < 4; ++dt)
                o[row * HDIM + h*HD + 16*dt + fr] = f2bf(O[mt][dt][rg] * lv[rg]);
        }
    }
#undef STAGE
}

// ---------------------------------------------------------------------------
extern "C" void kernel_launch(void* const* d_in, const int* in_sizes, int n_in,
                              void* d_out, int out_size, void* d_ws, size_t ws_size,
                              hipStream_t stream)
{
    const float* image_tokens = (const float*)d_in[0];
    const float* cond_tokens  = (const float*)d_in[1];
    const float* icos  = (const float*)d_in[2];
    const float* isin  = (const float*)d_in[3];
    const float* ccos  = (const float*)d_in[4];
    const float* csin  = (const float*)d_in[5];
    const float* img_n1w  = (const float*)d_in[6];
    const float* cond_n1w = (const float*)d_in[7];
    const float* img_qkv_w  = (const float*)d_in[8];
    const float* img_qkv_b  = (const float*)d_in[9];
    const float* cond_qkv_w = (const float*)d_in[10];
    const float* cond_qkv_b = (const float*)d_in[11];
    const float* img_qn  = (const float*)d_in[12];
    const float* img_kn  = (const float*)d_in[13];
    const float* cond_qn = (const float*)d_in[14];
    const float* cond_kn = (const float*)d_in[15];
    const float* img_out_w  = (const float*)d_in[16];
    const float* img_out_b  = (const float*)d_in[17];
    const float* cond_out_w = (const float*)d_in[18];
    const float* cond_out_b = (const float*)d_in[19];
    const float* img_n2w  = (const float*)d_in[20];
    const float* cond_n2w = (const float*)d_in[21];
    const float* img_w1 = (const float*)d_in[22];
    const float* img_b1 = (const float*)d_in[23];
    const float* img_w2 = (const float*)d_in[24];
    const float* img_b2 = (const float*)d_in[25];
    const float* img_w3 = (const float*)d_in[26];
    const float* img_b3 = (const float*)d_in[27];
    const float* cond_w1 = (const float*)d_in[28];
    const float* cond_b1 = (const float*)d_in[29];
    const float* cond_w2 = (const float*)d_in[30];
    const float* cond_b2 = (const float*)d_in[31];
    const float* cond_w3 = (const float*)d_in[32];
    const float* cond_b3 = (const float*)d_in[33];
    const float* alpha = (const float*)d_in[34];
    const float* beta  = (const float*)d_in[35];

    float* out = (float*)d_out;   // rows: img 0..2047, cond 2048..2559

    // Arena (unsigned short units). Peak 93.3 MB (R4-R11 proven).
    unsigned short* u = (unsigned short*)d_ws;
    unsigned short* wp_i  = u + 0;          // [8192][1024] pair img
    unsigned short* wp_c  = u + 8388608;
    unsigned short* w3b_i = u + 16777216;   // [1024][4096]
    unsigned short* w3b_c = u + 20971520;
    unsigned short* wqb_i = u + 25165824;   // [3072][1024]
    unsigned short* wqb_c = u + 28311552;
    unsigned short* wob_i = u + 31457280;   // [1024][1024]
    unsigned short* wob_c = u + 32505856;
    unsigned short* xn = u + 33554432;      // [2560][1024] (dead after qkv_gemm)
    unsigned short* vt = u + 36175872;      // [32][64][1280] (dead after attn)
    unsigned short* qh = u + 38797312;      // [32][1280][64] (dead after attn)
    unsigned short* kh = u + 41418752;      //   "
    unsigned short* o  = u + 44040192;      // [2560][1024] (dead after out-proj)
    float*          op = (float*)(u + 38797312);  // f32 [2560][1024] over qh+kh (dead)
    unsigned short* n2 = u + 36175872;      // over vt (dead after attn)
    unsigned short* hbf = u + 25165824;     // [2560][4096] over wq+wo+xn (dead)

    // 1. pack all weights + norm1 (seg 8), one dispatch
    pack_weights<<<dim3(640, 9), 256, 0, stream>>>(
        img_w1, img_w2, cond_w1, cond_w2, img_w3, cond_w3,
        img_qkv_w, cond_qkv_w, img_out_w, cond_out_w,
        wp_i, wp_c, w3b_i, w3b_c, wqb_i, wqb_c, wob_i, wob_c,
        image_tokens, cond_tokens, img_n1w, cond_n1w, xn);

    // 2. grouped qkv GEMM + fused rmsnorm/rope epilogue -> qh/kh + vt
    qkv_gemm<<<480, 256, 0, stream>>>(
        xn, wqb_i, wqb_c, img_qkv_b, cond_qkv_b,
        img_qn, img_kn, cond_qn, cond_kn, icos, isin, ccos, csin,
        qh, kh, vt);

    // 3. flash attention -> o (320 blocks, XCD-remapped)
    attn_mfma<<<320, 256, 0, stream>>>(qh, kh, vt, o);

    // 4. out-proj: op = bias; += o @ Wo^T (split-K=4 -> 640 blocks, atomic)
    op_init<<<MROWS, 256, 0, stream>>>(img_out_b, cond_out_b, op);
    skg_gemm<<<8 * MTT * 4, 256, 0, stream>>>(
        o, HDIM, wob_i, wob_c, op, HDIM / 4, nullptr, nullptr);

    // 5. fused norm2 + down-proj init
    norm2_down<<<MROWS, 256, 0, stream>>>(
        image_tokens, cond_tokens, op, img_n2w, cond_n2w,
        img_b3, cond_b3, alpha, beta, n2, out);

    // 6. pair GEMM (up1+up2, swiglu) -> hbf (1280 blocks, XCD-remapped)
    pair_gemm<<<1280, 256, 0, stream>>>(
        n2, wp_i, wp_c, img_b1, img_b2, cond_b1, cond_b2, hbf);

    // 7. down-proj + residuals -> out (split-K=8 -> 1280 blocks, atomic)
    skg_gemm<<<8 * MTT * 8, 256, 0, stream>>>(
        hbf, MLPD, w3b_i, w3b_c, out, MLPD / 8, beta, nullptr);
}

// Round 13
// 289.543 us; speedup vs baseline: 1.1398x; 1.1398x over previous
//
#include <hip/hip_runtime.h>
#include <hip/hip_bf16.h>

// Problem constants
#define BB   2
#define LI   1024
#define LC   256
#define SEQ  1280      // LC + LI
#define HDIM 1024
#define NH   16
#define HD   64
#define MLPD 4096
#define EPS  1e-6f
#define MROWS 2560     // 2048 img rows then 512 cond rows
#define MTI  16        // img M-tiles (BM=128)
#define MTT  20        // total M-tiles (16 img + 4 cond)

typedef __bf16 bf16x8 __attribute__((ext_vector_type(8)));
typedef float f32x4 __attribute__((ext_vector_type(4)));
typedef unsigned short us4 __attribute__((ext_vector_type(4)));

static __device__ __forceinline__ unsigned short f2bf(float f) {
    unsigned int u = __builtin_bit_cast(unsigned int, f);
    u += 0x7fffu + ((u >> 16) & 1u);
    return (unsigned short)(u >> 16);
}

// async global->LDS, 16B per lane. LDS dst = wave-uniform base + lane*16.
static __device__ __forceinline__ void gload_lds16(const void* g, void* l) {
    __builtin_amdgcn_global_load_lds((__attribute__((address_space(1))) void*)(g),
                                     (__attribute__((address_space(3))) void*)(l),
                                     16, 0, 0);
}

// ---------------------------------------------------------------------------
// One-shot weight pack + norm1. Segs 0/1: interleave w1/w2 (16-col groups) into
// pair layout [8192][1024]; segs 2-7: plain f32->bf16 cvt; seg 8: rmsnorm1
// (4 rows per block) -> xn bf16 [2560][1024].
__global__ __launch_bounds__(256)
void pack_weights(const float* __restrict__ w1i, const float* __restrict__ w2i,
                  const float* __restrict__ w1c, const float* __restrict__ w2c,
                  const float* __restrict__ w3i, const float* __restrict__ w3c,
                  const float* __restrict__ wqi, const float* __restrict__ wqc,
                  const float* __restrict__ woi, const float* __restrict__ woc,
                  unsigned short* __restrict__ wpi, unsigned short* __restrict__ wpc,
                  unsigned short* __restrict__ w3bi, unsigned short* __restrict__ w3bc,
                  unsigned short* __restrict__ wqbi, unsigned short* __restrict__ wqbc,
                  unsigned short* __restrict__ wobi, unsigned short* __restrict__ wobc,
                  const float* __restrict__ img_tok, const float* __restrict__ cond_tok,
                  const float* __restrict__ n1wi, const float* __restrict__ n1wc,
                  unsigned short* __restrict__ xn)
{
    const int seg = blockIdx.y;
    const int t = threadIdx.x;

    if (seg == 8) {   // rmsnorm1: rows blockIdx.x*4 .. +3
        __shared__ float red[4];
#pragma unroll
        for (int rr = 0; rr < 4; ++rr) {
            const int row = blockIdx.x * 4 + rr;
            const float* x = (row < 2048) ? img_tok + (size_t)row * HDIM
                                          : cond_tok + (size_t)(row - 2048) * HDIM;
            const float* w = (row < 2048) ? n1wi : n1wc;
            float4 v = ((const float4*)x)[t];
            float ss = v.x*v.x + v.y*v.y + v.z*v.z + v.w*v.w;
            for (int o = 32; o > 0; o >>= 1) ss += __shfl_xor(ss, o);
            if ((t & 63) == 0) red[t >> 6] = ss;
            __syncthreads();
            float inv = rsqrtf((red[0]+red[1]+red[2]+red[3]) * (1.0f / HDIM) + EPS);
            float4 wv = ((const float4*)w)[t];
            us4 pk = { f2bf(v.x*inv*wv.x), f2bf(v.y*inv*wv.y),
                       f2bf(v.z*inv*wv.z), f2bf(v.w*inv*wv.w) };
            *(us4*)&xn[(size_t)row * HDIM + t * 4] = pk;
            __syncthreads();   // red reused next iteration
        }
        return;
    }

    const float* s0 = nullptr; const float* s1 = nullptr;
    unsigned short* dst = nullptr; int n4 = 0; bool pair = false;
    switch (seg) {
        case 0: pair = true; s0 = w1i; s1 = w2i; dst = wpi;  n4 = 8388608 / 4; break;
        case 1: pair = true; s0 = w1c; s1 = w2c; dst = wpc;  n4 = 8388608 / 4; break;
        case 2: s0 = w3i; dst = w3bi; n4 = 4194304 / 4; break;
        case 3: s0 = w3c; dst = w3bc; n4 = 4194304 / 4; break;
        case 4: s0 = wqi; dst = wqbi; n4 = 3145728 / 4; break;
        case 5: s0 = wqc; dst = wqbc; n4 = 3145728 / 4; break;
        case 6: s0 = woi; dst = wobi; n4 = 1048576 / 4; break;
        case 7: s0 = woc; dst = wobc; n4 = 1048576 / 4; break;
    }
    for (int i = blockIdx.x * 256 + t; i < n4; i += gridDim.x * 256) {
        float4 v;
        if (pair) {
            int p  = i >> 8;          // phys row (256 float4 per 1024-row)
            int k4 = i & 255;
            int g = p >> 4, r = p & 15;
            const float* s = (g & 1) ? s1 : s0;
            v = *(const float4*)&s[((size_t)((g >> 1) * 16 + r)) * 1024 + k4 * 4];
        } else {
            v = ((const float4*)s0)[i];
        }
        us4 o = { f2bf(v.x), f2bf(v.y), f2bf(v.z), f2bf(v.w) };
        ((us4*)dst)[i] = o;
    }
}

// ---------------------------------------------------------------------------
// Fused norm2 + down-proj init. val = tok + sa*op;
// n2 = rmsnorm(val)*w (bf16);  out = val + sm*b3 (f32, split-K target).
__global__ __launch_bounds__(256)
void norm2_down(const float* __restrict__ img_tok, const float* __restrict__ cond_tok,
                const float* __restrict__ op, const float* __restrict__ wi,
                const float* __restrict__ wc, const float* __restrict__ b3i,
                const float* __restrict__ b3c, const float* __restrict__ alpha,
                const float* __restrict__ beta,
                unsigned short* __restrict__ n2, float* __restrict__ out)
{
    const int row = blockIdx.x;
    const int t   = threadIdx.x;
    const bool img = row < 2048;
    const float sa = img ? alpha[0] : 1.0f;
    const float sm = img ? beta[0]  : 1.0f;
    const float* tok = img ? img_tok + (size_t)row * HDIM
                           : cond_tok + (size_t)(row - 2048) * HDIM;
    const float* w  = img ? wi  : wc;
    const float* b3 = img ? b3i : b3c;
    float4 tv = ((const float4*)tok)[t];
    float4 ov = ((const float4*)(op + (size_t)row * HDIM))[t];
    float4 v = { tv.x + sa*ov.x, tv.y + sa*ov.y, tv.z + sa*ov.z, tv.w + sa*ov.w };
    float ss = v.x*v.x + v.y*v.y + v.z*v.z + v.w*v.w;
    for (int o = 32; o > 0; o >>= 1) ss += __shfl_xor(ss, o);
    __shared__ float red[4];
    if ((t & 63) == 0) red[t >> 6] = ss;
    __syncthreads();
    float inv = rsqrtf((red[0]+red[1]+red[2]+red[3]) * (1.0f / HDIM) + EPS);
    float4 wv = ((const float4*)w)[t];
    us4 pk = { f2bf(v.x*inv*wv.x), f2bf(v.y*inv*wv.y),
               f2bf(v.z*inv*wv.z), f2bf(v.w*inv*wv.w) };
    *(us4*)&n2[(size_t)row * HDIM + t * 4] = pk;
    float4 bv = ((const float4*)b3)[t];
    float4 o4 = { v.x + sm*bv.x, v.y + sm*bv.y, v.z + sm*bv.z, v.w + sm*bv.w };
    ((float4*)(out + (size_t)row * HDIM))[t] = o4;
}

// op = bias (broadcast), per-stream bias
__global__ __launch_bounds__(256)
void op_init(const float* __restrict__ bi, const float* __restrict__ bc,
             float* __restrict__ op)
{
    const int row = blockIdx.x, t = threadIdx.x;
    const float* b = (row < 2048) ? bi : bc;
    ((float4*)(op + (size_t)row * HDIM))[t] = ((const float4*)b)[t];
}

// ---------------------------------------------------------------------------
// Grouped QKV GEMM with FUSED per-head RMSNorm+RoPE epilogue (R9-proven).
// 1-D grid 480, XCD remap. 2-barrier BK=32 K-loop.
__global__ __launch_bounds__(256)
void qkv_gemm(const unsigned short* __restrict__ xn,
              const unsigned short* __restrict__ wqi, const unsigned short* __restrict__ wqc,
              const float* __restrict__ bi, const float* __restrict__ bc,
              const float* __restrict__ img_qn, const float* __restrict__ img_kn,
              const float* __restrict__ cond_qn, const float* __restrict__ cond_kn,
              const float* __restrict__ icos, const float* __restrict__ isin,
              const float* __restrict__ ccos, const float* __restrict__ csin,
              unsigned short* __restrict__ qh, unsigned short* __restrict__ kh,
              unsigned short* __restrict__ vt)
{
    __shared__ __align__(16) unsigned short As[128][32];
    __shared__ __align__(16) unsigned short Ws[128][32];

    const int id  = blockIdx.x;
    const int xcd = id & 7, idx = id >> 3;           // 8 x 60
    const int xcol = xcd * 3 + idx / 20;             // 0..23
    const int mt   = idx % 20;
    const bool img = mt < MTI;
    const int row0 = img ? mt * 128 : 2048 + (mt - MTI) * 128;
    const int grow0 = img ? mt * 128 : (mt - MTI) * 128;
    const unsigned short* W = img ? wqi : wqc;
    const float* bias = img ? bi : bc;
    const int bn = xcol * 128;

    const int t = threadIdx.x, lane = t & 63, wid = t >> 6;
    const int wm = wid >> 1, wn = wid & 1;
    const int srow = (wid << 5) + (lane >> 2);
    const int scol = (lane & 3) << 3;
    const unsigned short* Ag0 = xn + (size_t)(row0 + srow)      * HDIM + scol;
    const unsigned short* Ag1 = xn + (size_t)(row0 + srow + 16) * HDIM + scol;
    const unsigned short* Wg0 = W  + (size_t)(bn + srow)        * HDIM + scol;
    const unsigned short* Wg1 = W  + (size_t)(bn + srow + 16)   * HDIM + scol;
    unsigned short* lA0 = &As[(wid << 5)     ][0];
    unsigned short* lA1 = &As[(wid << 5) + 16][0];
    unsigned short* lW0 = &Ws[(wid << 5)     ][0];
    unsigned short* lW1 = &Ws[(wid << 5) + 16][0];

    const int fr = lane & 15, kg = lane >> 4, ko = kg << 3;
    f32x4 acc[4][4] = {};

    for (int k0 = 0; k0 < HDIM; k0 += 32) {
        __syncthreads();
        gload_lds16(Ag0 + k0, lA0);
        gload_lds16(Ag1 + k0, lA1);
        gload_lds16(Wg0 + k0, lW0);
        gload_lds16(Wg1 + k0, lW1);
        __syncthreads();
        bf16x8 aF[4], bF[4];
#pragma unroll
        for (int m = 0; m < 4; ++m) aF[m] = *(const bf16x8*)&As[wm*64 + m*16 + fr][ko];
#pragma unroll
        for (int n = 0; n < 4; ++n) bF[n] = *(const bf16x8*)&Ws[wn*64 + n*16 + fr][ko];
#pragma unroll
        for (int m = 0; m < 4; ++m)
#pragma unroll
            for (int n = 0; n < 4; ++n)
                acc[m][n] = __builtin_amdgcn_mfma_f32_16x16x32_bf16(aF[m], bF[n], acc[m][n], 0,0,0);
    }

    // ---- epilogue: wave-uniform head / q-k-v selector ----
    const int gcbase = bn + wn * 64;     // 64-aligned, uniform per wave
    const int which  = gcbase >> 10;     // 0 q / 1 k / 2 v
    const int h      = (gcbase >> 6) & 15;

    if (which == 2) {
#pragma unroll
        for (int n = 0; n < 4; ++n) {
            const int d = n*16 + fr;
            const float bv = bias[gcbase + d];
#pragma unroll
            for (int m = 0; m < 4; ++m) {
                const int gl0 = grow0 + wm*64 + m*16 + (kg << 2);
                int b, s0;
                if (img) { b = gl0 >> 10; s0 = LC + (gl0 & 1023); }
                else     { b = gl0 >> 8;  s0 = gl0 & 255; }
                us4 pk = { f2bf(acc[m][n][0] + bv), f2bf(acc[m][n][1] + bv),
                           f2bf(acc[m][n][2] + bv), f2bf(acc[m][n][3] + bv) };
                *(us4*)&vt[(((size_t)(b*NH + h)) * HD + d) * SEQ + s0] = pk;
            }
        }
    } else {
        unsigned short* dst = (which == 0) ? qh : kh;
        const float qscale = (which == 0) ? 0.125f : 1.0f;
        const float* nw = img ? (which == 0 ? img_qn : img_kn)
                              : (which == 0 ? cond_qn : cond_kn);
        const float* cs_tab = img ? icos : ccos;
        const float* sn_tab = img ? isin : csin;
        float wv[4], bv[4];
#pragma unroll
        for (int nt = 0; nt < 4; ++nt) {
            wv[nt] = nw[nt*16 + fr];
            bv[nt] = bias[gcbase + nt*16 + fr];
        }
#pragma unroll
        for (int m = 0; m < 4; ++m) {
#pragma unroll
            for (int j = 0; j < 4; ++j) {
                const int gl = grow0 + wm*64 + m*16 + (kg << 2) + j;
                int b, srel, s;
                if (img) { b = gl >> 10; srel = gl & 1023; s = LC + srel; }
                else     { b = gl >> 8;  srel = gl & 255;  s = srel; }
                float v[4];
                float ss = 0.f;
#pragma unroll
                for (int nt = 0; nt < 4; ++nt) {
                    v[nt] = acc[m][nt][j] + bv[nt];
                    ss += v[nt] * v[nt];
                }
                ss += __shfl_xor(ss, 1);
                ss += __shfl_xor(ss, 2);
                ss += __shfl_xor(ss, 4);
                ss += __shfl_xor(ss, 8);
                const float inv = rsqrtf(ss * (1.0f / HD) + EPS);
                float xv[4];
#pragma unroll
                for (int nt = 0; nt < 4; ++nt) xv[nt] = v[nt] * inv * wv[nt];
                const size_t obase = (((size_t)(b*NH + h)) * SEQ + s) * HD;
#pragma unroll
                for (int nt = 0; nt < 4; ++nt) {
                    const int d = nt*16 + fr;
                    const float rot = (nt < 2) ? -xv[nt + 2] : xv[nt - 2];
                    const float c  = cs_tab[(size_t)srel * HD + d];
                    const float sn = sn_tab[(size_t)srel * HD + d];
                    dst[obase + d] = f2bf((xv[nt] * c + rot * sn) * qscale);
                }
            }
        }
    }
}

// ---------------------------------------------------------------------------
// Grouped pair GEMM (R6-proven form). 1-D grid 1280, XCD remap: xcd owns 8
// col-tiles. 2-barrier BK=32 K-loop. swiglu epilogue -> hbf.
__global__ __launch_bounds__(256)
void pair_gemm(const unsigned short* __restrict__ n2,
               const unsigned short* __restrict__ wpi, const unsigned short* __restrict__ wpc,
               const float* __restrict__ b1i, const float* __restrict__ b2i,
               const float* __restrict__ b1c, const float* __restrict__ b2c,
               unsigned short* __restrict__ hbf)
{
    __shared__ __align__(16) unsigned short As[128][32];
    __shared__ __align__(16) unsigned short Ws[128][32];

    const int id  = blockIdx.x;
    const int xcd = id & 7, idx = id >> 3;           // 8 x 160
    const int x   = xcd * 8 + idx / 20;              // phys col tile 0..63
    const int mt  = idx % 20;
    const bool img = mt < MTI;
    const int row0 = img ? mt * 128 : 2048 + (mt - MTI) * 128;
    const unsigned short* W = img ? wpi : wpc;
    const float* b1 = img ? b1i : b1c;
    const float* b2 = img ? b2i : b2c;
    const int bn = x * 128;

    const int t = threadIdx.x, lane = t & 63, wid = t >> 6;
    const int wm = wid >> 1, wn = wid & 1;
    const int srow = (wid << 5) + (lane >> 2);
    const int scol = (lane & 3) << 3;
    const unsigned short* Ag0 = n2 + (size_t)(row0 + srow)      * HDIM + scol;
    const unsigned short* Ag1 = n2 + (size_t)(row0 + srow + 16) * HDIM + scol;
    const unsigned short* Wg0 = W  + (size_t)(bn + srow)        * HDIM + scol;
    const unsigned short* Wg1 = W  + (size_t)(bn + srow + 16)   * HDIM + scol;
    unsigned short* lA0 = &As[(wid << 5)     ][0];
    unsigned short* lA1 = &As[(wid << 5) + 16][0];
    unsigned short* lW0 = &Ws[(wid << 5)     ][0];
    unsigned short* lW1 = &Ws[(wid << 5) + 16][0];

    const int fr = lane & 15, kg = lane >> 4, ko = kg << 3;
    f32x4 acc[4][4] = {};

    for (int k0 = 0; k0 < HDIM; k0 += 32) {
        __syncthreads();
        gload_lds16(Ag0 + k0, lA0);
        gload_lds16(Ag1 + k0, lA1);
        gload_lds16(Wg0 + k0, lW0);
        gload_lds16(Wg1 + k0, lW1);
        __syncthreads();
        bf16x8 aF[4], bF[4];
#pragma unroll
        for (int m = 0; m < 4; ++m) aF[m] = *(const bf16x8*)&As[wm*64 + m*16 + fr][ko];
#pragma unroll
        for (int n = 0; n < 4; ++n) bF[n] = *(const bf16x8*)&Ws[wn*64 + n*16 + fr][ko];
#pragma unroll
        for (int m = 0; m < 4; ++m)
#pragma unroll
            for (int n = 0; n < 4; ++n)
                acc[m][n] = __builtin_amdgcn_mfma_f32_16x16x32_bf16(aF[m], bF[n], acc[m][n], 0,0,0);
    }

    // epilogue: pairs (nt=0,1) and (nt=2,3): logical col lc = (4x+2wn+p)*16+fr
#pragma unroll
    for (int p = 0; p < 2; ++p) {
        const int lc = (4*x + 2*wn + p) * 16 + fr;        // 0..4095
        const float b1v = b1[lc], b2v = b2[lc];
#pragma unroll
        for (int m = 0; m < 4; ++m) {
#pragma unroll
            for (int j = 0; j < 4; ++j) {
                const int row = row0 + wm*64 + m*16 + (kg << 2) + j;
                float g1 = acc[m][2*p    ][j] + b1v;
                float g2 = acc[m][2*p + 1][j] + b2v;
                float hv = (g1 / (1.0f + __expf(-g1))) * g2;
                hbf[(size_t)row * MLPD + lc] = f2bf(hv);
            }
        }
    }
}

// ---------------------------------------------------------------------------
// Grouped split-K GEMM, 128x128, N=1024, BK=32. 1-D grid 8*20*Z (20Z%8==0).
// A-OWNING XCD remap: each XCD owns (20Z)/8 (mt,kz) pairs; its 8 bn-blocks
// share the A chunk + small W k-slice (L2-resident). Epilogue: atomics.
__global__ __launch_bounds__(256)
void skg_gemm(const unsigned short* __restrict__ A, int K,
              const unsigned short* __restrict__ Wimg, const unsigned short* __restrict__ Wcond,
              float* __restrict__ out, int kchunk,
              const float* __restrict__ sci, const float* __restrict__ scc)
{
    __shared__ __align__(16) unsigned short As[128][32];
    __shared__ __align__(16) unsigned short Ws[128][32];

    const int id  = blockIdx.x;
    const int xcd = id & 7;
    const int j   = id >> 3;                  // 0 .. 20Z-1
    const int ppx = gridDim.x >> 6;           // pairs per XCD = (20Z)/8
    const int pair = xcd * ppx + (j >> 3);    // 0 .. 20Z-1
    const int bn  = (j & 7) * 128;
    const int kz  = pair / 20;
    const int mt  = pair % 20;
    const bool img = mt < MTI;
    const int row0 = img ? mt * 128 : 2048 + (mt - MTI) * 128;
    const unsigned short* W = img ? Wimg : Wcond;
    const float sc = img ? (sci ? sci[0] : 1.0f) : (scc ? scc[0] : 1.0f);
    const int kbase = kz * kchunk;

    const int t = threadIdx.x, lane = t & 63, wid = t >> 6;
    const int wm = wid >> 1, wn = wid & 1;
    const int srow = (wid << 5) + (lane >> 2);
    const int scol = (lane & 3) << 3;
    const unsigned short* Ag0 = A + (size_t)(row0 + srow)      * K + kbase + scol;
    const unsigned short* Ag1 = A + (size_t)(row0 + srow + 16) * K + kbase + scol;
    const unsigned short* Wg0 = W + (size_t)(bn + srow)        * K + kbase + scol;
    const unsigned short* Wg1 = W + (size_t)(bn + srow + 16)   * K + kbase + scol;
    unsigned short* lA0 = &As[(wid << 5)     ][0];
    unsigned short* lA1 = &As[(wid << 5) + 16][0];
    unsigned short* lW0 = &Ws[(wid << 5)     ][0];
    unsigned short* lW1 = &Ws[(wid << 5) + 16][0];

    const int fr = lane & 15, kg = lane >> 4, ko = kg << 3;
    f32x4 acc[4][4] = {};

    for (int k0 = 0; k0 < kchunk; k0 += 32) {
        __syncthreads();
        gload_lds16(Ag0 + k0, lA0);
        gload_lds16(Ag1 + k0, lA1);
        gload_lds16(Wg0 + k0, lW0);
        gload_lds16(Wg1 + k0, lW1);
        __syncthreads();
        bf16x8 aF[4], bF[4];
#pragma unroll
        for (int m = 0; m < 4; ++m) aF[m] = *(const bf16x8*)&As[wm*64 + m*16 + fr][ko];
#pragma unroll
        for (int n = 0; n < 4; ++n) bF[n] = *(const bf16x8*)&Ws[wn*64 + n*16 + fr][ko];
#pragma unroll
        for (int m = 0; m < 4; ++m)
#pragma unroll
            for (int n = 0; n < 4; ++n)
                acc[m][n] = __builtin_amdgcn_mfma_f32_16x16x32_bf16(aF[m], bF[n], acc[m][n], 0,0,0);
    }

#pragma unroll
    for (int n = 0; n < 4; ++n) {
        const int col = bn + wn*64 + n*16 + fr;
#pragma unroll
        for (int m = 0; m < 4; ++m) {
            const int r0 = row0 + wm*64 + m*16 + (kg << 2);
#pragma unroll
            for (int j2 = 0; j2 < 4; ++j2)
                unsafeAtomicAdd(&out[(size_t)(r0 + j2) * HDIM + col], sc * acc[m][n][j2]);
        }
    }
}

// ---------------------------------------------------------------------------
// MFMA flash attention: 256 thr (4 waves), q-tile 128. 1-D grid 320 with
// XCD remap (4 bh per XCD -> K/V L2-resident). Double-buffered staging;
// S^T = mfma(K,Q); packed us4 P writes.
__global__ __launch_bounds__(256)
void attn_mfma(const unsigned short* __restrict__ qg,
               const unsigned short* __restrict__ kg,
               const unsigned short* __restrict__ vtg,
               unsigned short* __restrict__ o)
{
    const int id  = blockIdx.x;
    const int xcd = id & 7, idx = id >> 3;     // 8 x 40
    const int bh  = xcd * 4 + idx / 10;        // 0..31
    const int q0  = (idx % 10) * 128;
    const int h   = bh & 15;
    const int b   = bh >> 4;
    const int t   = threadIdx.x;
    const int wid = t >> 6;
    const int lane = t & 63;
    const int g  = lane >> 4;
    const int fr = lane & 15;

    __shared__ __align__(16) unsigned short Ks [2][64 * 64];
    __shared__ __align__(16) unsigned short VTs[2][64 * 64];
    __shared__ __align__(16) unsigned short Ps [4][32][72];

    const unsigned short* qb  = qg  + (size_t)bh * SEQ * HD;
    const unsigned short* kb  = kg  + (size_t)bh * SEQ * HD;
    const unsigned short* vtb = vtg + (size_t)bh * HD * SEQ;

    bf16x8 Qf[2][2];
#pragma unroll
    for (int mt = 0; mt < 2; ++mt)
#pragma unroll
        for (int kc = 0; kc < 2; ++kc)
            Qf[mt][kc] = *(const bf16x8*)&qb[(size_t)(q0 + wid*32 + mt*16 + fr) * HD
                                             + kc*32 + g*8];

    f32x4 O[2][4] = {};
    float mreg[2] = { -3e38f, -3e38f };
    float lreg[2] = { 0.f, 0.f };

#define STAGE(tile_, bufi_)                                                     \
    {                                                                           \
        _Pragma("unroll")                                                       \
        for (int i = 0; i < 2; ++i) {                                           \
            int chbase = i * 256 + wid * 64;                                    \
            int ch = chbase + lane;                                             \
            int r = ch >> 3, c = ch & 7;                                        \
            int cs_ = c ^ (r & 7);                                              \
            gload_lds16(kb  + (size_t)((tile_)*64 + r) * HD + cs_*8,            \
                        &Ks[bufi_][chbase * 8]);                                \
            gload_lds16(vtb + (size_t)r * SEQ + (tile_)*64 + cs_*8,             \
                        &VTs[bufi_][chbase * 8]);                               \
        }                                                                       \
    }

    STAGE(0, 0);
    __syncthreads();
    int buf = 0;

    for (int tile = 0; tile < SEQ / 64; ++tile) {
        if (tile + 1 < SEQ / 64) STAGE(tile + 1, buf ^ 1);

        f32x4 ST[2][4] = {};
#pragma unroll
        for (int kc = 0; kc < 2; ++kc)
#pragma unroll
            for (int nt = 0; nt < 4; ++nt) {
                int r = fr + 16*nt;
                bf16x8 kf = *(const bf16x8*)&Ks[buf][r*64 + (((g + 4*kc) ^ (r & 7)) * 8)];
#pragma unroll
                for (int mt = 0; mt < 2; ++mt)
                    ST[mt][nt] = __builtin_amdgcn_mfma_f32_16x16x32_bf16(
                        kf, Qf[mt][kc], ST[mt][nt], 0, 0, 0);
            }

#pragma unroll
        for (int mt = 0; mt < 2; ++mt) {
            float tm = -3e38f;
#pragma unroll
            for (int nt = 0; nt < 4; ++nt)
#pragma unroll
                for (int j = 0; j < 4; ++j) tm = fmaxf(tm, ST[mt][nt][j]);
            tm = fmaxf(tm, __shfl_xor(tm, 16));
            tm = fmaxf(tm, __shfl_xor(tm, 32));
            float mn = fmaxf(mreg[mt], tm);
            float al = __expf(mreg[mt] - mn);
            mreg[mt] = mn;
            float ls = 0.f;
#pragma unroll
            for (int nt = 0; nt < 4; ++nt) {
#pragma unroll
                for (int j = 0; j < 4; ++j) {
                    float p = __expf(ST[mt][nt][j] - mn);
                    ST[mt][nt][j] = p;
                    ls += p;
                }
            }
            ls += __shfl_xor(ls, 16);
            ls += __shfl_xor(ls, 32);
            lreg[mt] = al * lreg[mt] + ls;
            f32x4 alr;
#pragma unroll
            for (int rg = 0; rg < 4; ++rg) alr[rg] = __shfl(al, 4*g + rg);
#pragma unroll
            for (int dt = 0; dt < 4; ++dt) O[mt][dt] *= alr;
#pragma unroll
            for (int nt = 0; nt < 4; ++nt) {
                us4 pk = { f2bf(ST[mt][nt][0]), f2bf(ST[mt][nt][1]),
                           f2bf(ST[mt][nt][2]), f2bf(ST[mt][nt][3]) };
                *(us4*)&Ps[wid][mt*16 + fr][16*nt + 4*g] = pk;
            }
        }

#pragma unroll
        for (int kc = 0; kc < 2; ++kc) {
            bf16x8 Pf[2];
#pragma unroll
            for (int mt = 0; mt < 2; ++mt)
                Pf[mt] = *(const bf16x8*)&Ps[wid][mt*16 + fr][kc*32 + g*8];
#pragma unroll
            for (int dt = 0; dt < 4; ++dt) {
                int r = fr + 16*dt;
                bf16x8 vf = *(const bf16x8*)&VTs[buf][r*64 + (((g + 4*kc) ^ (r & 7)) * 8)];
#pragma unroll
                for (int mt = 0; mt < 2; ++mt)
                    O[mt][dt] = __builtin_amdgcn_mfma_f32_16x16x32_bf16(
                        Pf[mt], vf, O[mt][dt], 0, 0, 0);
            }
        }

        __syncthreads();
        buf ^= 1;
    }

#pragma unroll
    for (int mt = 0; mt < 2; ++mt) {
        const float linv = 1.0f / lreg[mt];
        f32x4 lv;
#pragma unroll
        for (int rg = 0; rg < 4; ++rg) lv[rg] = __shfl(linv, 4*g + rg);
#pragma unroll
        for (int rg = 0; rg < 4; ++rg) {
            const int s_tok = q0 + wid*32 + mt*16 + 4*g + rg;
            const size_t row = (s_tok < LC) ? (size_t)(2048 + b*LC + s_tok)
                                            : (size_t)(b*LI + (s_tok - LC));
#pragma unroll
            for (int dt = 0; dt < 4; ++dt)
                o[row * HDIM + h*HD + 16*dt + fr] = f2bf(O[mt][dt][rg] * lv[rg]);
        }
    }
#undef STAGE
}

// ---------------------------------------------------------------------------
extern "C" void kernel_launch(void* const* d_in, const int* in_sizes, int n_in,
                              void* d_out, int out_size, void* d_ws, size_t ws_size,
                              hipStream_t stream)
{
    const float* image_tokens = (const float*)d_in[0];
    const float* cond_tokens  = (const float*)d_in[1];
    const float* icos  = (const float*)d_in[2];
    const float* isin  = (const float*)d_in[3];
    const float* ccos  = (const float*)d_in[4];
    const float* csin  = (const float*)d_in[5];
    const float* img_n1w  = (const float*)d_in[6];
    const float* cond_n1w = (const float*)d_in[7];
    const float* img_qkv_w  = (const float*)d_in[8];
    const float* img_qkv_b  = (const float*)d_in[9];
    const float* cond_qkv_w = (const float*)d_in[10];
    const float* cond_qkv_b = (const float*)d_in[11];
    const float* img_qn  = (const float*)d_in[12];
    const float* img_kn  = (const float*)d_in[13];
    const float* cond_qn = (const float*)d_in[14];
    const float* cond_kn = (const float*)d_in[15];
    const float* img_out_w  = (const float*)d_in[16];
    const float* img_out_b  = (const float*)d_in[17];
    const float* cond_out_w = (const float*)d_in[18];
    const float* cond_out_b = (const float*)d_in[19];
    const float* img_n2w  = (const float*)d_in[20];
    const float* cond_n2w = (const float*)d_in[21];
    const float* img_w1 = (const float*)d_in[22];
    const float* img_b1 = (const float*)d_in[23];
    const float* img_w2 = (const float*)d_in[24];
    const float* img_b2 = (const float*)d_in[25];
    const float* img_w3 = (const float*)d_in[26];
    const float* img_b3 = (const float*)d_in[27];
    const float* cond_w1 = (const float*)d_in[28];
    const float* cond_b1 = (const float*)d_in[29];
    const float* cond_w2 = (const float*)d_in[30];
    const float* cond_b2 = (const float*)d_in[31];
    const float* cond_w3 = (const float*)d_in[32];
    const float* cond_b3 = (const float*)d_in[33];
    const float* alpha = (const float*)d_in[34];
    const float* beta  = (const float*)d_in[35];

    float* out = (float*)d_out;   // rows: img 0..2047, cond 2048..2559

    // Arena (unsigned short units). Peak 93.3 MB (R4-R12 proven).
    unsigned short* u = (unsigned short*)d_ws;
    unsigned short* wp_i  = u + 0;          // [8192][1024] pair img
    unsigned short* wp_c  = u + 8388608;
    unsigned short* w3b_i = u + 16777216;   // [1024][4096]
    unsigned short* w3b_c = u + 20971520;
    unsigned short* wqb_i = u + 25165824;   // [3072][1024]
    unsigned short* wqb_c = u + 28311552;
    unsigned short* wob_i = u + 31457280;   // [1024][1024]
    unsigned short* wob_c = u + 32505856;
    unsigned short* xn = u + 33554432;      // [2560][1024] (dead after qkv_gemm)
    unsigned short* vt = u + 36175872;      // [32][64][1280] (dead after attn)
    unsigned short* qh = u + 38797312;      // [32][1280][64] (dead after attn)
    unsigned short* kh = u + 41418752;      //   "
    unsigned short* o  = u + 44040192;      // [2560][1024] (dead after out-proj)
    float*          op = (float*)(u + 38797312);  // f32 [2560][1024] over qh+kh (dead)
    unsigned short* n2 = u + 36175872;      // over vt (dead after attn)
    unsigned short* hbf = u + 25165824;     // [2560][4096] over wq+wo+xn (dead)

    // 1. pack all weights + norm1 (seg 8), one dispatch
    pack_weights<<<dim3(640, 9), 256, 0, stream>>>(
        img_w1, img_w2, cond_w1, cond_w2, img_w3, cond_w3,
        img_qkv_w, cond_qkv_w, img_out_w, cond_out_w,
        wp_i, wp_c, w3b_i, w3b_c, wqb_i, wqb_c, wob_i, wob_c,
        image_tokens, cond_tokens, img_n1w, cond_n1w, xn);

    // 2. grouped qkv GEMM + fused rmsnorm/rope epilogue -> qh/kh + vt
    qkv_gemm<<<480, 256, 0, stream>>>(
        xn, wqb_i, wqb_c, img_qkv_b, cond_qkv_b,
        img_qn, img_kn, cond_qn, cond_kn, icos, isin, ccos, csin,
        qh, kh, vt);

    // 3. flash attention -> o (320 blocks, XCD-remapped)
    attn_mfma<<<320, 256, 0, stream>>>(qh, kh, vt, o);

    // 4. out-proj: op = bias; += o @ Wo^T (split-K=2, A-owning remap)
    op_init<<<MROWS, 256, 0, stream>>>(img_out_b, cond_out_b, op);
    skg_gemm<<<8 * MTT * 2, 256, 0, stream>>>(
        o, HDIM, wob_i, wob_c, op, HDIM / 2, nullptr, nullptr);

    // 5. fused norm2 + down-proj init
    norm2_down<<<MROWS, 256, 0, stream>>>(
        image_tokens, cond_tokens, op, img_n2w, cond_n2w,
        img_b3, cond_b3, alpha, beta, n2, out);

    // 6. pair GEMM (up1+up2, swiglu) -> hbf (1280 blocks, XCD-remapped)
    pair_gemm<<<1280, 256, 0, stream>>>(
        n2, wp_i, wp_c, img_b1, img_b2, cond_b1, cond_b2, hbf);

    // 7. down-proj + residuals -> out (split-K=4, A-owning remap)
    skg_gemm<<<8 * MTT * 4, 256, 0, stream>>>(
        hbf, MLPD, w3b_i, w3b_c, out, MLPD / 4, beta, nullptr);
}